// Round 2
// baseline (1275.710 us; speedup 1.0000x reference)
//
#include <hip/hip_runtime.h>

typedef short short8_t __attribute__((ext_vector_type(8)));
typedef __bf16 bf16x8  __attribute__((ext_vector_type(8)));
typedef float f32x4    __attribute__((ext_vector_type(4)));

union FragU { short4 h[2]; short8_t s; bf16x8 b; };

__device__ __forceinline__ unsigned short bf16rne(float f){
  unsigned u = __float_as_uint(f);
  unsigned r = u + 0x7FFFu + ((u >> 16) & 1u);
  return (unsigned short)(r >> 16);
}
__device__ __forceinline__ float bf2f(unsigned short h){
  return __uint_as_float(((unsigned)h) << 16);
}

#define MFMA(A,B,C) __builtin_amdgcn_mfma_f32_16x16x32_bf16((A),(B),(C),0,0,0)

// ---- ws byte offsets ----
#define OFF_SUM    0        // 256 f32 column sums
#define OFF_SUMSQ  1024     // 256 f32 column sumsq
#define OFF_SCALE  2048     // 256 f32 (floats idx 512)
#define OFF_SHIFT  3072     // 256 f32 (floats idx 768)
#define OFF_NORMA  4096     // 16 f32  (floats idx 1024)
#define OFF_B2P    4160     // 128 f32 (floats idx 1040)
#define OFF_W1T    8192     // hi 65536 B, lo 65536 B   [kc4][nt16][lane64][e8] bf16
#define OFF_W2T    139264   // hi 65536 B, lo 65536 B   [kc8][nt8][lane64][e8]  (W2' = scale-folded)
#define OFF_WE     270336   // 10 experts x (We1hi 16384 + We1lo 16384 + We2 2048)
#define WE_STRIDE  34816
#define OFF_ATTRT  618496   // 4096 B [kc4][lane64][e8]

// ---------------- K0: weight prep (frag-major, hi/lo split), zero stats, normA ----------------
__global__ __launch_bounds__(256) void k_prep(const float* __restrict__ W1,
                                              const float* __restrict__ We1,
                                              const float* __restrict__ We2,
                                              const float* __restrict__ attr,
                                              char* __restrict__ ws){
  int gid = blockIdx.x * 256 + threadIdx.x;
  float* wsf = (float*)ws;
  if (gid < 512) wsf[gid] = 0.f;                       // zero gsum/gsumsq
  if (blockIdx.x == 0 && threadIdx.x < 16){            // normA
    float s = 0.f;
    if (threadIdx.x < 10){
      const float* a = attr + threadIdx.x * 128;
      for (int e = 0; e < 128; ++e) s += a[e] * a[e];
    }
    wsf[OFF_NORMA/4 + threadIdx.x] = s;
  }
  int idx = gid;
  if (idx < 32768){                                    // W1T hi/lo
    int i = idx & 7, l = (idx >> 3) & 63, nt = (idx >> 9) & 15, kc = idx >> 13;
    int k = kc*32 + ((i >> 2) << 4) + ((l >> 4) << 2) + (i & 3);
    int n = nt*16 + (l & 15);
    float v = (k < 100) ? W1[k*256 + n] : 0.f;
    unsigned short hi = bf16rne(v);
    unsigned short lo = bf16rne(v - bf2f(hi));
    ((unsigned short*)(ws + OFF_W1T))[idx] = hi;
    ((unsigned short*)(ws + OFF_W1T + 65536))[idx] = lo;
    return;
  }
  idx -= 32768;
  if (idx < 81920){                                    // We1T hi/lo per expert
    int ke = idx >> 13, sub = idx & 8191;
    int i = sub & 7, l = (sub >> 3) & 63, nt = (sub >> 9) & 3, kc = sub >> 11;
    int k = kc*32 + ((i >> 2) << 4) + ((l >> 4) << 2) + (i & 3);   // e-dim 0..127
    int n = nt*16 + (l & 15);                                      // h-dim 0..63
    float v = We1[ke*8192 + k*64 + n];
    unsigned short hi = bf16rne(v);
    unsigned short lo = bf16rne(v - bf2f(hi));
    char* base = ws + OFF_WE + ke*WE_STRIDE;
    ((unsigned short*)base)[sub] = hi;
    ((unsigned short*)(base + 16384))[sub] = lo;
    return;
  }
  idx -= 81920;
  if (idx < 10240){                                    // We2T plain
    int ke = idx >> 10, sub = idx & 1023;
    int i = sub & 7, l = (sub >> 3) & 63, kc = sub >> 9;
    int k = kc*32 + ((i >> 2) << 4) + ((l >> 4) << 2) + (i & 3);   // h-dim 0..63
    int n = l & 15;                                                // action
    float v = (n < 10) ? We2[ke*640 + k*10 + n] : 0.f;
    ((unsigned short*)(ws + OFF_WE + ke*WE_STRIDE + 32768))[sub] = bf16rne(v);
    return;
  }
  idx -= 10240;
  if (idx < 2048){                                     // attrT plain
    int i = idx & 7, l = (idx >> 3) & 63, kc = idx >> 9;
    int k = kc*32 + ((i >> 2) << 4) + ((l >> 4) << 2) + (i & 3);   // e-dim
    int n = l & 15;
    float v = (n < 10) ? attr[n*128 + k] : 0.f;
    ((unsigned short*)(ws + OFF_ATTRT))[idx] = bf16rne(v);
  }
}

// ---------------- finalize BN stats -> scale/shift ----------------
__global__ void k_finalize(const float* __restrict__ gamma, const float* __restrict__ beta,
                           char* __restrict__ ws){
  int c = threadIdx.x;
  float* f = (float*)ws;
  const float inv = 1.f / 262144.f;
  float mu  = f[c] * inv;
  float var = f[256 + c] * inv - mu * mu;
  float sc  = gamma[c] * rsqrtf(var + 1e-5f);
  f[512 + c] = sc;
  f[768 + c] = beta[c] - mu * sc;
}

// ---------------- W2' = diag(scale)*W2 (frag-major hi/lo) and b2' ----------------
__global__ __launch_bounds__(256) void k_prep2(const float* __restrict__ W2,
                                               const float* __restrict__ b2,
                                               char* __restrict__ ws){
  float* f = (float*)ws;
  if (blockIdx.x == 128){
    int n = threadIdx.x;
    if (n < 128){
      float s = b2[n];
      for (int k = 0; k < 256; ++k) s += f[768 + k] * W2[k*128 + n];
      f[OFF_B2P/4 + n] = s;
    }
    return;
  }
  int idx = blockIdx.x * 256 + threadIdx.x;            // 0..32767
  int i = idx & 7, l = (idx >> 3) & 63, nt = (idx >> 9) & 7, kc = idx >> 12;
  int k = kc*32 + ((i >> 2) << 4) + ((l >> 4) << 2) + (i & 3);
  int n = nt*16 + (l & 15);
  float v = W2[k*128 + n] * f[512 + k];
  unsigned short hi = bf16rne(v);
  unsigned short lo = bf16rne(v - bf2f(hi));
  ((unsigned short*)(ws + OFF_W2T))[idx] = hi;
  ((unsigned short*)(ws + OFF_W2T + 65536))[idx] = lo;
}

// ---------------- fragment helpers ----------------
__device__ __forceinline__ bf16x8 afrag(const short* buf, int RB, int row, int kc, int lq){
  int swz = (row & 7) << 4;
  int rb  = row * RB;
  int c0  = kc*64 + lq*8;
  FragU f;
  f.h[0] = *(const short4*)(buf + ((rb + ( c0       ^ swz)) >> 1));
  f.h[1] = *(const short4*)(buf + ((rb + ((c0 + 32) ^ swz)) >> 1));
  return f.b;
}
__device__ __forceinline__ bf16x8 gfrag(const char* p){
  FragU f;
  f.s = *(const short8_t*)p;
  return f.b;
}
__device__ __forceinline__ void astore(short* buf, int RB, int row, int colb, unsigned short v){
  buf[(row*RB + (colb ^ ((row & 7) << 4))) >> 1] = (short)v;
}

// stage one 64x100 state tile as bf16-hi into swizzled [64][128] (RB=256B)
__device__ __forceinline__ void stageS(short* dst, const float* src, int tid){
  for (int q = tid; q < 1600; q += 256){
    int row = q / 25, kq = q - row*25;
    float4 v = *(const float4*)(src + (size_t)row*100 + kq*4);
    int off = (row*256 + ((kq*8) ^ ((row & 7) << 4))) >> 1;
    *(short4*)(dst + off) = make_short4((short)bf16rne(v.x),(short)bf16rne(v.y),
                                        (short)bf16rne(v.z),(short)bf16rne(v.w));
  }
}

// ---------------- stats pass: column sums of relu(state@W1+b1), 4 tiles/block ----------------
__global__ __launch_bounds__(256, 4) void k_stats(const float* __restrict__ state,
                                                  const float* __restrict__ b1,
                                                  char* __restrict__ ws){
  __shared__ __align__(16) short A[16384];   // 2 x [64][128] bf16 swizzled
  const int tid = threadIdx.x;
  const int w = tid >> 6, l = tid & 63, lq = l >> 4, lr = l & 15;
  // zero-pad k=100..127 in both buffers (data region never touches it)
  for (int q = tid; q < 896; q += 256){
    int b = q >= 448, qq = q - b*448;
    int row = qq / 7, j = qq - row*7;
    int off = (row*256 + ((200 + j*8) ^ ((row & 7) << 4))) >> 1;
    *(short4*)(A + b*8192 + off) = make_short4(0,0,0,0);
  }
  float b1v[4];
  #pragma unroll
  for (int ntl = 0; ntl < 4; ++ntl) b1v[ntl] = b1[(w*4 + ntl)*16 + lr];
  float s4[4] = {0,0,0,0}, q4[4] = {0,0,0,0};
  stageS(A, state + (size_t)(blockIdx.x*4)*6400, tid);
  const char* w1hi = ws + OFF_W1T;
  #pragma unroll 1
  for (int t = 0; t < 4; ++t){
    __syncthreads();
    if (t < 3) stageS(A + ((t+1)&1)*8192, state + (size_t)(blockIdx.x*4 + t + 1)*6400, tid);
    const short* Ab = A + (t&1)*8192;
    f32x4 acc[4][4];
    #pragma unroll
    for (int a = 0; a < 4; ++a)
      #pragma unroll
      for (int b = 0; b < 4; ++b) acc[a][b] = (f32x4){0.f,0.f,0.f,0.f};
    #pragma unroll 1
    for (int kc = 0; kc < 4; ++kc){
      bf16x8 ah[4];
      #pragma unroll
      for (int mt = 0; mt < 4; ++mt) ah[mt] = afrag(Ab, 256, mt*16 + lr, kc, lq);
      #pragma unroll
      for (int ntl = 0; ntl < 4; ++ntl){
        bf16x8 bh = gfrag(w1hi + kc*16384 + (w*4 + ntl)*1024 + l*16);
        #pragma unroll
        for (int mt = 0; mt < 4; ++mt) acc[mt][ntl] = MFMA(ah[mt], bh, acc[mt][ntl]);
      }
    }
    #pragma unroll
    for (int ntl = 0; ntl < 4; ++ntl)
      #pragma unroll
      for (int mt = 0; mt < 4; ++mt)
        #pragma unroll
        for (int r = 0; r < 4; ++r){
          float h = fmaxf(acc[mt][ntl][r] + b1v[ntl], 0.f);
          s4[ntl] += h; q4[ntl] += h*h;
        }
  }
  float* gsum = (float*)ws;
  float* gsq  = (float*)(ws + OFF_SUMSQ);
  #pragma unroll
  for (int ntl = 0; ntl < 4; ++ntl){
    float s = s4[ntl], q = q4[ntl];
    s += __shfl_xor(s, 16); s += __shfl_xor(s, 32);
    q += __shfl_xor(q, 16); q += __shfl_xor(q, 32);
    if (l < 16){
      int col = (w*4 + ntl)*16 + lr;
      atomicAdd(&gsum[col], s);
      atomicAdd(&gsq[col], q);
    }
  }
}

// ---------------- fused main pass ----------------
__global__ __launch_bounds__(256, 3) void k_fused(const float* __restrict__ state,
                                                  const float* __restrict__ b1,
                                                  const float* __restrict__ be1,
                                                  const float* __restrict__ be2,
                                                  const char* __restrict__ ws,
                                                  float* __restrict__ out){
  __shared__ __align__(16) short U[16384];   // 32KB union: A1h/A1l -> Hh/Hl -> Eh/El -> outbuf
  __shared__ __align__(16) short X[8320];    // 16KB ehT dbuf + 64 f32 normE
  const int tid = threadIdx.x;
  const int w = tid >> 6, l = tid & 63, lq = l >> 4, lr = l & 15;
  const int row0 = blockIdx.x * 64;

  // ---- stage state tile hi/lo ----
  short* A1h = U;
  short* A1l = U + 8192;
  for (int q = tid; q < 448; q += 256){
    int row = q / 7, j = q - row*7;
    int off = (row*256 + ((200 + j*8) ^ ((row & 7) << 4))) >> 1;
    *(short4*)(A1h + off) = make_short4(0,0,0,0);
    *(short4*)(A1l + off) = make_short4(0,0,0,0);
  }
  for (int q = tid; q < 1600; q += 256){
    int row = q / 25, kq = q - row*25;
    float4 v = *(const float4*)(state + (size_t)(row0 + row)*100 + kq*4);
    int off = (row*256 + ((kq*8) ^ ((row & 7) << 4))) >> 1;
    unsigned short h0 = bf16rne(v.x), h1 = bf16rne(v.y), h2 = bf16rne(v.z), h3 = bf16rne(v.w);
    *(short4*)(A1h + off) = make_short4((short)h0,(short)h1,(short)h2,(short)h3);
    unsigned short o0 = bf16rne(v.x - bf2f(h0)), o1 = bf16rne(v.y - bf2f(h1));
    unsigned short o2 = bf16rne(v.z - bf2f(h2)), o3 = bf16rne(v.w - bf2f(h3));
    *(short4*)(A1l + off) = make_short4((short)o0,(short)o1,(short)o2,(short)o3);
  }
  float b1v[4];
  #pragma unroll
  for (int ntl = 0; ntl < 4; ++ntl) b1v[ntl] = b1[(w*4 + ntl)*16 + lr];
  __syncthreads();

  // ---- GEMM1 (3-term): B frags straight from global (L2-hot) ----
  f32x4 acc1[4][4];
  #pragma unroll
  for (int a = 0; a < 4; ++a)
    #pragma unroll
    for (int b = 0; b < 4; ++b) acc1[a][b] = (f32x4){0.f,0.f,0.f,0.f};
  const char* w1hi = ws + OFF_W1T;
  const char* w1lo = w1hi + 65536;
  #pragma unroll 1
  for (int kc = 0; kc < 4; ++kc){
    bf16x8 ah[4], al[4];
    #pragma unroll
    for (int mt = 0; mt < 4; ++mt){
      ah[mt] = afrag(A1h, 256, mt*16 + lr, kc, lq);
      al[mt] = afrag(A1l, 256, mt*16 + lr, kc, lq);
    }
    #pragma unroll
    for (int ntl = 0; ntl < 4; ++ntl){
      int nb = kc*16384 + (w*4 + ntl)*1024 + l*16;
      bf16x8 bh = gfrag(w1hi + nb);
      bf16x8 bl = gfrag(w1lo + nb);
      #pragma unroll
      for (int mt = 0; mt < 4; ++mt){
        acc1[mt][ntl] = MFMA(ah[mt], bh, acc1[mt][ntl]);
        acc1[mt][ntl] = MFMA(al[mt], bh, acc1[mt][ntl]);
        acc1[mt][ntl] = MFMA(ah[mt], bl, acc1[mt][ntl]);
      }
    }
  }

  // ---- GEMM2 in two k-halves through 32KB h buffer ----
  short* Hh = U;
  short* Hl = U + 8192;
  const char* w2hi = ws + OFF_W2T;
  const char* w2lo = w2hi + 65536;
  const float* b2pf = (const float*)(ws + OFF_B2P);
  f32x4 acc2[4][2];
  #pragma unroll
  for (int a = 0; a < 4; ++a){ acc2[a][0] = (f32x4){0.f,0.f,0.f,0.f}; acc2[a][1] = (f32x4){0.f,0.f,0.f,0.f}; }
  #pragma unroll 1
  for (int hf = 0; hf < 2; ++hf){
    __syncthreads();                         // prior reads of U done
    if ((w >> 1) == hf){                     // waves owning cols hf*128..+127 write h hi/lo
      #pragma unroll
      for (int ntl = 0; ntl < 4; ++ntl){
        int colb = ((w & 1)*64 + ntl*16 + lr) * 2;
        #pragma unroll
        for (int mt = 0; mt < 4; ++mt)
          #pragma unroll
          for (int r = 0; r < 4; ++r){
            int row = mt*16 + lq*4 + r;
            float h = fmaxf(acc1[mt][ntl][r] + b1v[ntl], 0.f);
            unsigned short hi = bf16rne(h);
            unsigned short lo = bf16rne(h - bf2f(hi));
            astore(Hh, 256, row, colb, hi);
            astore(Hl, 256, row, colb, lo);
          }
      }
    }
    __syncthreads();
    #pragma unroll 1
    for (int kcl = 0; kcl < 4; ++kcl){
      bf16x8 ah[4], al[4];
      #pragma unroll
      for (int mt = 0; mt < 4; ++mt){
        ah[mt] = afrag(Hh, 256, mt*16 + lr, kcl, lq);
        al[mt] = afrag(Hl, 256, mt*16 + lr, kcl, lq);
      }
      #pragma unroll
      for (int ntl = 0; ntl < 2; ++ntl){
        int nb = (hf*4 + kcl)*8192 + (w*2 + ntl)*1024 + l*16;
        bf16x8 bh = gfrag(w2hi + nb);
        bf16x8 bl = gfrag(w2lo + nb);
        #pragma unroll
        for (int mt = 0; mt < 4; ++mt){
          acc2[mt][ntl] = MFMA(ah[mt], bh, acc2[mt][ntl]);
          acc2[mt][ntl] = MFMA(al[mt], bh, acc2[mt][ntl]);
          acc2[mt][ntl] = MFMA(ah[mt], bl, acc2[mt][ntl]);
        }
      }
    }
  }

  // ---- enc = tanh(.): write hi/lo, load fragments to regs ----
  __syncthreads();
  short* Eh = U;
  short* El = U + 8192;
  #pragma unroll
  for (int ntl = 0; ntl < 2; ++ntl){
    int col = (w*2 + ntl)*16 + lr;
    float bb = b2pf[col];
    #pragma unroll
    for (int mt = 0; mt < 4; ++mt)
      #pragma unroll
      for (int r = 0; r < 4; ++r){
        int row = mt*16 + lq*4 + r;
        float x = acc2[mt][ntl][r] + bb;
        x = fminf(fmaxf(x, -30.f), 30.f);
        float e = __expf(-2.f * x);
        float t = (1.f - e) / (1.f + e);
        unsigned short hi = bf16rne(t);
        unsigned short lo = bf16rne(t - bf2f(hi));
        astore(Eh, 256, row, col*2, hi);
        astore(El, 256, row, col*2, lo);
      }
  }
  __syncthreads();
  bf16x8 efh[4][4], efl[4][4];
  #pragma unroll
  for (int mt = 0; mt < 4; ++mt)
    #pragma unroll
    for (int kc = 0; kc < 4; ++kc){
      efh[mt][kc] = afrag(Eh, 256, mt*16 + lr, kc, lq);
      efl[mt][kc] = afrag(El, 256, mt*16 + lr, kc, lq);
    }

  // ---- normE (wave 0 writes), distance GEMM ----
  float* normE = (float*)(X + 8192);
  #pragma unroll
  for (int mt = 0; mt < 4; ++mt){
    float s = 0.f;
    #pragma unroll
    for (int kc = 0; kc < 4; ++kc)
      #pragma unroll
      for (int e = 0; e < 8; ++e){
        float v = (float)efh[mt][kc][e] + (float)efl[mt][kc][e];
        s += v * v;
      }
    s += __shfl_xor(s, 16); s += __shfl_xor(s, 32);
    if (w == 0 && l < 16) normE[mt*16 + lr] = s;
  }
  const char* att = ws + OFF_ATTRT;
  f32x4 accd = (f32x4){0.f,0.f,0.f,0.f};
  #pragma unroll
  for (int kc = 0; kc < 4; ++kc){
    bf16x8 bfA = gfrag(att + kc*1024 + l*16);
    accd = MFMA(efh[w][kc], bfA, accd);
    accd = MFMA(efl[w][kc], bfA, accd);
  }
  __syncthreads();                           // normE visible

  // ---- softmax strengths (rows w*16+lq*4+r, ke = lr) ----
  const float* normAf = (const float*)(ws + OFF_NORMA);
  float nA = (lr < 10) ? normAf[lr] : 0.f;
  float sv[4];
  #pragma unroll
  for (int r = 0; r < 4; ++r){
    int row = w*16 + lq*4 + r;
    float d2 = normE[row] + nA - 2.f * accd[r];
    float dist = sqrtf(fmaxf(d2, 0.f));
    float logit = (lr < 10) ? (-2.f * dist) : -3.0e38f;
    float m = logit;
    #pragma unroll
    for (int o = 1; o < 16; o <<= 1) m = fmaxf(m, __shfl_xor(m, o));
    float e = __expf(logit - m);
    float ssum = e;
    #pragma unroll
    for (int o = 1; o < 16; o <<= 1) ssum += __shfl_xor(ssum, o);
    sv[r] = e / ssum;
  }

  // ---- expert loop: E1 (2-term) -> ehT dbuf -> E2 -> online output accum ----
  f32x4 out_acc = (f32x4){0.f,0.f,0.f,0.f};
  const char* webase = ws + OFF_WE;
  #pragma unroll 1
  for (int ke = 0; ke < 10; ++ke){
    const char* wb = webase + ke*WE_STRIDE;
    f32x4 acce[4];
    #pragma unroll
    for (int mt = 0; mt < 4; ++mt) acce[mt] = (f32x4){0.f,0.f,0.f,0.f};
    #pragma unroll
    for (int kc = 0; kc < 4; ++kc){
      bf16x8 bh = gfrag(wb + kc*4096 + w*1024 + l*16);
      #pragma unroll
      for (int mt = 0; mt < 4; ++mt){
        acce[mt] = MFMA(efh[mt][kc], bh, acce[mt]);
        acce[mt] = MFMA(efl[mt][kc], bh, acce[mt]);
      }
    }
    short* eb = X + (ke & 1)*4096;           // [64][64] bf16 swizzled, RB=128
    float bev = be1[ke*64 + w*16 + lr];
    #pragma unroll
    for (int mt = 0; mt < 4; ++mt)
      #pragma unroll
      for (int r = 0; r < 4; ++r){
        int row = mt*16 + lq*4 + r;
        float v = fmaxf(acce[mt][r] + bev, 0.f);
        astore(eb, 128, row, (w*16 + lr)*2, bf16rne(v));
      }
    __syncthreads();
    f32x4 habk = (f32x4){0.f,0.f,0.f,0.f};
    #pragma unroll
    for (int kc2 = 0; kc2 < 2; ++kc2){
      bf16x8 af = afrag(eb, 128, w*16 + lr, kc2, lq);
      bf16x8 bf2 = gfrag(wb + 32768 + kc2*1024 + l*16);
      habk = MFMA(af, bf2, habk);
    }
    float be2v = (lr < 10) ? be2[ke*10 + lr] : 0.f;
    #pragma unroll
    for (int r = 0; r < 4; ++r){
      float sk = __shfl(sv[r], (l & 48) | ke);
      out_acc[r] += (habk[r] + be2v) * sk;
    }
  }

  // ---- coalesced output via LDS ----
  float* ob = (float*)U;                     // 640 f32 (Eh region, dead)
  #pragma unroll
  for (int r = 0; r < 4; ++r)
    if (lr < 10) ob[(w*16 + lq*4 + r)*10 + lr] = out_acc[r];
  __syncthreads();
  if (tid < 160) *(float4*)(out + (size_t)row0*10 + tid*4) = *(const float4*)(ob + tid*4);
}

extern "C" void kernel_launch(void* const* d_in, const int* in_sizes, int n_in,
                              void* d_out, int out_size, void* d_ws, size_t ws_size,
                              hipStream_t stream){
  const float* state = (const float*)d_in[0];
  const float* W1    = (const float*)d_in[1];
  const float* b1    = (const float*)d_in[2];
  const float* gamma = (const float*)d_in[3];
  const float* beta  = (const float*)d_in[4];
  const float* W2    = (const float*)d_in[5];
  const float* b2    = (const float*)d_in[6];
  const float* We1   = (const float*)d_in[7];
  const float* be1   = (const float*)d_in[8];
  const float* We2   = (const float*)d_in[9];
  const float* be2   = (const float*)d_in[10];
  const float* attr  = (const float*)d_in[11];
  char* ws  = (char*)d_ws;
  float* out = (float*)d_out;

  k_prep<<<496, 256, 0, stream>>>(W1, We1, We2, attr, ws);
  k_stats<<<1024, 256, 0, stream>>>(state, b1, ws);
  k_finalize<<<1, 256, 0, stream>>>(gamma, beta, ws);
  k_prep2<<<129, 256, 0, stream>>>(W2, b2, ws);
  k_fused<<<4096, 256, 0, stream>>>(state, b1, be1, be2, ws, out);
}

// Round 5
// 448.417 us; speedup vs baseline: 2.8449x; 2.8449x over previous
//
#include <hip/hip_runtime.h>

typedef short short8_t __attribute__((ext_vector_type(8)));
typedef __bf16 bf16x8  __attribute__((ext_vector_type(8)));
typedef float f32x4    __attribute__((ext_vector_type(4)));

union FragU { short4 h[2]; short8_t s; bf16x8 b; };

__device__ __forceinline__ unsigned short bf16rne(float f){
  unsigned u = __float_as_uint(f);
  unsigned r = u + 0x7FFFu + ((u >> 16) & 1u);
  return (unsigned short)(r >> 16);
}
__device__ __forceinline__ float bf2f(unsigned short h){
  return __uint_as_float(((unsigned)h) << 16);
}
__device__ __forceinline__ int swzb(int row){ return ((row & 7) << 4) | (row & 8); }

__device__ __forceinline__ f32x4 ntload4(const float* p){
  return __builtin_nontemporal_load((const f32x4*)p);
}
__device__ __forceinline__ void ntstore4(float* p, f32x4 v){
  __builtin_nontemporal_store(v, (f32x4*)p);
}

#define MFMA(A,B,C) __builtin_amdgcn_mfma_f32_16x16x32_bf16((A),(B),(C),0,0,0)

// ---- ws byte offsets ----
#define OFF_SUM    0        // 256 f32 column sums
#define OFF_SUMSQ  1024     // 256 f32 column sumsq
#define OFF_NORMA  4096     // 16 f32  (floats idx 1024)
#define OFF_B2P    4160     // 128 f32 (floats idx 1040)
#define OFF_W1T    8192     // hi 65536 B, lo 65536 B   [kc4][nt16][lane64][e8] bf16
#define OFF_W2T    139264   // hi 65536 B, lo 65536 B   [kc8][nt8][lane64][e8]  (W2' = scale-folded)
#define OFF_WE     270336   // 10 experts x (We1hi 16384 + hole 16384 + We2 2048)
#define WE_STRIDE  34816
#define OFF_ATTRT  618496   // 4096 B [kc4][lane64][e8]

// ---------------- K0: weight prep (frag-major), zero stats, normA ----------------
__global__ __launch_bounds__(256) void k_prep(const float* __restrict__ W1,
                                              const float* __restrict__ We1,
                                              const float* __restrict__ We2,
                                              const float* __restrict__ attr,
                                              char* __restrict__ ws){
  int gid = blockIdx.x * 256 + threadIdx.x;
  float* wsf = (float*)ws;
  if (gid < 512) wsf[gid] = 0.f;                       // zero gsum/gsumsq
  if (blockIdx.x == 0 && threadIdx.x < 16){            // normA
    float s = 0.f;
    if (threadIdx.x < 10){
      const float* a = attr + threadIdx.x * 128;
      for (int e = 0; e < 128; ++e) s += a[e] * a[e];
    }
    wsf[OFF_NORMA/4 + threadIdx.x] = s;
  }
  int idx = gid;
  if (idx < 32768){                                    // W1T hi/lo
    int i = idx & 7, l = (idx >> 3) & 63, nt = (idx >> 9) & 15, kc = idx >> 13;
    int k = kc*32 + ((i >> 2) << 4) + ((l >> 4) << 2) + (i & 3);
    int n = nt*16 + (l & 15);
    float v = (k < 100) ? W1[k*256 + n] : 0.f;
    unsigned short hi = bf16rne(v);
    unsigned short lo = bf16rne(v - bf2f(hi));
    ((unsigned short*)(ws + OFF_W1T))[idx] = hi;
    ((unsigned short*)(ws + OFF_W1T + 65536))[idx] = lo;
    return;
  }
  idx -= 32768;
  if (idx < 81920){                                    // We1T hi per expert
    int ke = idx >> 13, sub = idx & 8191;
    int i = sub & 7, l = (sub >> 3) & 63, nt = (sub >> 9) & 3, kc = sub >> 11;
    int k = kc*32 + ((i >> 2) << 4) + ((l >> 4) << 2) + (i & 3);   // e-dim 0..127
    int n = nt*16 + (l & 15);                                      // h-dim 0..63
    float v = We1[ke*8192 + k*64 + n];
    char* base = ws + OFF_WE + ke*WE_STRIDE;
    ((unsigned short*)base)[sub] = bf16rne(v);
    return;
  }
  idx -= 81920;
  if (idx < 10240){                                    // We2T plain
    int ke = idx >> 10, sub = idx & 1023;
    int i = sub & 7, l = (sub >> 3) & 63, kc = sub >> 9;
    int k = kc*32 + ((i >> 2) << 4) + ((l >> 4) << 2) + (i & 3);   // h-dim 0..63
    int n = l & 15;                                                // action
    float v = (n < 10) ? We2[ke*640 + k*10 + n] : 0.f;
    ((unsigned short*)(ws + OFF_WE + ke*WE_STRIDE + 32768))[sub] = bf16rne(v);
    return;
  }
  idx -= 10240;
  if (idx < 2048){                                     // attrT plain
    int i = idx & 7, l = (idx >> 3) & 63, kc = idx >> 9;
    int k = kc*32 + ((i >> 2) << 4) + ((l >> 4) << 2) + (i & 3);   // e-dim
    int n = l & 15;
    float v = (n < 10) ? attr[n*128 + k] : 0.f;
    ((unsigned short*)(ws + OFF_ATTRT))[idx] = bf16rne(v);
  }
}

// ---------------- finalize BN stats -> scale/shift ----------------
__global__ void k_finalize(const float* __restrict__ gamma, const float* __restrict__ beta,
                           char* __restrict__ ws){
  int c = threadIdx.x;
  float* f = (float*)ws;
  const float inv = 1.f / 262144.f;
  float mu  = f[c] * inv;
  float var = f[256 + c] * inv - mu * mu;
  float sc  = gamma[c] * rsqrtf(var + 1e-5f);
  f[512 + c] = sc;
  f[768 + c] = beta[c] - mu * sc;
}

// ---------------- W2' = diag(scale)*W2 (frag-major hi/lo) and b2' ----------------
__global__ __launch_bounds__(256) void k_prep2(const float* __restrict__ W2,
                                               const float* __restrict__ b2,
                                               char* __restrict__ ws){
  float* f = (float*)ws;
  if (blockIdx.x == 128){
    int n = threadIdx.x;
    if (n < 128){
      float s = b2[n];
      #pragma unroll 4
      for (int k = 0; k < 256; ++k) s += f[768 + k] * W2[k*128 + n];
      f[OFF_B2P/4 + n] = s;
    }
    return;
  }
  int idx = blockIdx.x * 256 + threadIdx.x;            // 0..32767
  int i = idx & 7, l = (idx >> 3) & 63, nt = (idx >> 9) & 7, kc = idx >> 12;
  int k = kc*32 + ((i >> 2) << 4) + ((l >> 4) << 2) + (i & 3);
  int n = nt*16 + (l & 15);
  float v = W2[k*128 + n] * f[512 + k];
  unsigned short hi = bf16rne(v);
  unsigned short lo = bf16rne(v - bf2f(hi));
  ((unsigned short*)(ws + OFF_W2T))[idx] = hi;
  ((unsigned short*)(ws + OFF_W2T + 65536))[idx] = lo;
}

// ---------------- fragment helpers ----------------
__device__ __forceinline__ bf16x8 afrag(const short* buf, int RB, int row, int kc, int lq){
  int swz = swzb(row);
  int rb  = row * RB;
  int c0  = kc*64 + lq*8;
  FragU f;
  f.h[0] = *(const short4*)(buf + ((rb + ( c0       ^ swz)) >> 1));
  f.h[1] = *(const short4*)(buf + ((rb + ((c0 + 32) ^ swz)) >> 1));
  return f.b;
}
__device__ __forceinline__ bf16x8 gfrag(const char* p){
  FragU f;
  f.s = *(const short8_t*)p;
  return f.b;
}
__device__ __forceinline__ void astore(short* buf, int RB, int row, int colb, unsigned short v){
  buf[(row*RB + (colb ^ swzb(row))) >> 1] = (short)v;
}

// stage one 64x100 state tile as bf16-hi into swizzled [64][128] (RB=256B), nt loads
__device__ __forceinline__ void stageS(short* dst, const float* src, int tid){
  for (int q = tid; q < 1600; q += 256){
    int row = q / 25, kq = q - row*25;
    f32x4 v = ntload4(src + (size_t)row*100 + kq*4);
    int off = (row*256 + ((kq*8) ^ swzb(row))) >> 1;
    *(short4*)(dst + off) = make_short4((short)bf16rne(v[0]),(short)bf16rne(v[1]),
                                        (short)bf16rne(v[2]),(short)bf16rne(v[3]));
  }
}

// ---------------- stats pass: column sums of relu(state@W1+b1), 4 tiles/block ----------------
__global__ __launch_bounds__(256, 4) void k_stats(const float* __restrict__ state,
                                                  const float* __restrict__ b1,
                                                  char* __restrict__ ws){
  __shared__ __align__(16) short A[16384];   // 2 x [64][128] bf16 swizzled
  const int tid = threadIdx.x;
  const int w = tid >> 6, l = tid & 63, lq = l >> 4, lr = l & 15;
  for (int q = tid; q < 896; q += 256){      // zero-pad k=100..127 both buffers
    int b = q >= 448, qq = q - b*448;
    int row = qq / 7, j = qq - row*7;
    int off = (row*256 + ((200 + j*8) ^ swzb(row))) >> 1;
    *(short4*)(A + b*8192 + off) = make_short4(0,0,0,0);
  }
  float b1v[4];
  #pragma unroll
  for (int ntl = 0; ntl < 4; ++ntl) b1v[ntl] = b1[(w*4 + ntl)*16 + lr];
  float s4[4] = {0,0,0,0}, q4[4] = {0,0,0,0};
  stageS(A, state + (size_t)(blockIdx.x*4)*6400, tid);
  const char* w1hi = ws + OFF_W1T;
  #pragma unroll 1
  for (int t = 0; t < 4; ++t){
    __syncthreads();
    if (t < 3) stageS(A + ((t+1)&1)*8192, state + (size_t)(blockIdx.x*4 + t + 1)*6400, tid);
    const short* Ab = A + (t&1)*8192;
    f32x4 acc[4][4];
    #pragma unroll
    for (int a = 0; a < 4; ++a)
      #pragma unroll
      for (int b = 0; b < 4; ++b) acc[a][b] = (f32x4){0.f,0.f,0.f,0.f};
    #pragma unroll 1
    for (int kc = 0; kc < 4; ++kc){
      bf16x8 ah[4];
      #pragma unroll
      for (int mt = 0; mt < 4; ++mt) ah[mt] = afrag(Ab, 256, mt*16 + lr, kc, lq);
      #pragma unroll
      for (int ntl = 0; ntl < 4; ++ntl){
        bf16x8 bh = gfrag(w1hi + kc*16384 + (w*4 + ntl)*1024 + l*16);
        #pragma unroll
        for (int mt = 0; mt < 4; ++mt) acc[mt][ntl] = MFMA(ah[mt], bh, acc[mt][ntl]);
      }
    }
    #pragma unroll
    for (int ntl = 0; ntl < 4; ++ntl)
      #pragma unroll
      for (int mt = 0; mt < 4; ++mt)
        #pragma unroll
        for (int r = 0; r < 4; ++r){
          float h = fmaxf(acc[mt][ntl][r] + b1v[ntl], 0.f);
          s4[ntl] += h; q4[ntl] += h*h;
        }
  }
  float* gsum = (float*)ws;
  float* gsq  = (float*)(ws + OFF_SUMSQ);
  #pragma unroll
  for (int ntl = 0; ntl < 4; ++ntl){
    float s = s4[ntl], q = q4[ntl];
    s += __shfl_xor(s, 16); s += __shfl_xor(s, 32);
    q += __shfl_xor(q, 16); q += __shfl_xor(q, 32);
    if (l < 16){
      int col = (w*4 + ntl)*16 + lr;
      atomicAdd(&gsum[col], s);
      atomicAdd(&gsq[col], q);
    }
  }
}

// ---------------- fused main pass ----------------
__global__ __launch_bounds__(256, 2) void k_fused(const float* __restrict__ state,
                                                  const float* __restrict__ b1,
                                                  const float* __restrict__ be1,
                                                  const float* __restrict__ be2,
                                                  const char* __restrict__ ws,
                                                  float* __restrict__ out){
  __shared__ __align__(16) short U[16384];   // 32KB union: A1h|A1l -> Hh -> (Eh | outbuf)
  __shared__ __align__(16) short X[8704];    // ehT dbuf: 2 x [64][68] shorts
  __shared__ float normE[64];
  const int tid = threadIdx.x;
  const int w = tid >> 6, l = tid & 63, lq = l >> 4, lr = l & 15;
  const int row0 = blockIdx.x * 64;

  // ---- stage state tile hi/lo ----
  short* A1h = U;
  short* A1l = U + 8192;
  for (int q = tid; q < 448; q += 256){      // zero-pad k=100..127
    int row = q / 7, j = q - row*7;
    int off = (row*256 + ((200 + j*8) ^ swzb(row))) >> 1;
    *(short4*)(A1h + off) = make_short4(0,0,0,0);
    *(short4*)(A1l + off) = make_short4(0,0,0,0);
  }
  for (int q = tid; q < 1600; q += 256){
    int row = q / 25, kq = q - row*25;
    f32x4 v = ntload4(state + (size_t)(row0 + row)*100 + kq*4);
    int off = (row*256 + ((kq*8) ^ swzb(row))) >> 1;
    unsigned short h0 = bf16rne(v[0]), h1 = bf16rne(v[1]), h2 = bf16rne(v[2]), h3 = bf16rne(v[3]);
    *(short4*)(A1h + off) = make_short4((short)h0,(short)h1,(short)h2,(short)h3);
    unsigned short o0 = bf16rne(v[0] - bf2f(h0)), o1 = bf16rne(v[1] - bf2f(h1));
    unsigned short o2 = bf16rne(v[2] - bf2f(h2)), o3 = bf16rne(v[3] - bf2f(h3));
    *(short4*)(A1l + off) = make_short4((short)o0,(short)o1,(short)o2,(short)o3);
  }
  float b1v[4];
  #pragma unroll
  for (int ntl = 0; ntl < 4; ++ntl) b1v[ntl] = b1[(w*4 + ntl)*16 + lr];
  __syncthreads();

  // ---- GEMM1 (3-term): B frags from global (L2-resident; state is nt) ----
  f32x4 acc1[4][4];
  #pragma unroll
  for (int a = 0; a < 4; ++a)
    #pragma unroll
    for (int b = 0; b < 4; ++b) acc1[a][b] = (f32x4){0.f,0.f,0.f,0.f};
  const char* w1hi = ws + OFF_W1T;
  const char* w1lo = w1hi + 65536;
  #pragma unroll 1
  for (int kc = 0; kc < 4; ++kc){
    bf16x8 ah[4], al[4];
    #pragma unroll
    for (int mt = 0; mt < 4; ++mt){
      ah[mt] = afrag(A1h, 256, mt*16 + lr, kc, lq);
      al[mt] = afrag(A1l, 256, mt*16 + lr, kc, lq);
    }
    #pragma unroll
    for (int ntl = 0; ntl < 4; ++ntl){
      int nb = kc*16384 + (w*4 + ntl)*1024 + l*16;
      bf16x8 bh = gfrag(w1hi + nb);
      bf16x8 bl = gfrag(w1lo + nb);
      #pragma unroll
      for (int mt = 0; mt < 4; ++mt){
        acc1[mt][ntl] = MFMA(ah[mt], bh, acc1[mt][ntl]);
        acc1[mt][ntl] = MFMA(al[mt], bh, acc1[mt][ntl]);
        acc1[mt][ntl] = MFMA(ah[mt], bl, acc1[mt][ntl]);
      }
    }
  }
  __syncthreads();                           // all A1 reads done

  // ---- write h (1-term bf16) ----
  short* Hh = U;                             // [64][256] shorts, RB=512B
  #pragma unroll
  for (int ntl = 0; ntl < 4; ++ntl){
    int colb = ((w*4 + ntl)*16 + lr) * 2;
    #pragma unroll
    for (int mt = 0; mt < 4; ++mt)
      #pragma unroll
      for (int r = 0; r < 4; ++r){
        int row = mt*16 + lq*4 + r;
        float h = fmaxf(acc1[mt][ntl][r] + b1v[ntl], 0.f);
        astore(Hh, 512, row, colb, bf16rne(h));
      }
  }
  __syncthreads();

  // ---- GEMM2 (2-term: h_hi x (W2'hi + W2'lo)) ----
  f32x4 acc2[4][2];
  #pragma unroll
  for (int a = 0; a < 4; ++a){ acc2[a][0] = (f32x4){0.f,0.f,0.f,0.f}; acc2[a][1] = (f32x4){0.f,0.f,0.f,0.f}; }
  const char* w2hi = ws + OFF_W2T;
  const char* w2lo = w2hi + 65536;
  #pragma unroll 2
  for (int kc = 0; kc < 8; ++kc){
    bf16x8 ah[4];
    #pragma unroll
    for (int mt = 0; mt < 4; ++mt) ah[mt] = afrag(Hh, 512, mt*16 + lr, kc, lq);
    #pragma unroll
    for (int ntl = 0; ntl < 2; ++ntl){
      int nb = kc*8192 + (w*2 + ntl)*1024 + l*16;
      bf16x8 bh = gfrag(w2hi + nb);
      bf16x8 bl = gfrag(w2lo + nb);
      #pragma unroll
      for (int mt = 0; mt < 4; ++mt){
        acc2[mt][ntl] = MFMA(ah[mt], bh, acc2[mt][ntl]);
        acc2[mt][ntl] = MFMA(ah[mt], bl, acc2[mt][ntl]);
      }
    }
  }
  __syncthreads();                           // all Hh reads done

  // ---- enc = tanh(.) 1-term bf16 ----
  short* Eh = U;                             // [64][128] shorts, RB=256B
  const float* b2pf = (const float*)(ws + OFF_B2P);
  #pragma unroll
  for (int ntl = 0; ntl < 2; ++ntl){
    int col = (w*2 + ntl)*16 + lr;
    float bb = b2pf[col];
    #pragma unroll
    for (int mt = 0; mt < 4; ++mt)
      #pragma unroll
      for (int r = 0; r < 4; ++r){
        int row = mt*16 + lq*4 + r;
        float x = acc2[mt][ntl][r] + bb;
        x = fminf(fmaxf(x, -30.f), 30.f);
        float e = __expf(-2.f * x);
        float t = (1.f - e) / (1.f + e);
        astore(Eh, 256, row, col*2, bf16rne(t));
      }
  }
  __syncthreads();

  // ---- enc fragments to regs; normE; distance GEMM ----
  bf16x8 efh[4][4];
  #pragma unroll
  for (int mt = 0; mt < 4; ++mt)
    #pragma unroll
    for (int kc = 0; kc < 4; ++kc) efh[mt][kc] = afrag(Eh, 256, mt*16 + lr, kc, lq);

  #pragma unroll
  for (int mt = 0; mt < 4; ++mt){
    float s = 0.f;
    #pragma unroll
    for (int kc = 0; kc < 4; ++kc)
      #pragma unroll
      for (int e = 0; e < 8; ++e){
        float v = (float)efh[mt][kc][e];
        s += v * v;
      }
    s += __shfl_xor(s, 16); s += __shfl_xor(s, 32);
    if (w == 0 && l < 16) normE[mt*16 + lr] = s;
  }
  const char* att = ws + OFF_ATTRT;
  f32x4 accd = (f32x4){0.f,0.f,0.f,0.f};
  #pragma unroll
  for (int kc = 0; kc < 4; ++kc)
    accd = MFMA(efh[w][kc], gfrag(att + kc*1024 + l*16), accd);
  __syncthreads();                           // normE visible

  // ---- softmax strengths (rows w*16+lq*4+r, ke = lr) ----
  const float* normAf = (const float*)(ws + OFF_NORMA);
  float nA = (lr < 10) ? normAf[lr] : 0.f;
  float sv[4];
  #pragma unroll
  for (int r = 0; r < 4; ++r){
    int row = w*16 + lq*4 + r;
    float d2 = normE[row] + nA - 2.f * accd[r];
    float dist = sqrtf(fmaxf(d2, 0.f));
    float logit = (lr < 10) ? (-2.f * dist) : -3.0e38f;
    float m = logit;
    #pragma unroll
    for (int o = 1; o < 16; o <<= 1) m = fmaxf(m, __shfl_xor(m, o));
    float e = __expf(logit - m);
    float ssum = e;
    #pragma unroll
    for (int o = 1; o < 16; o <<= 1) ssum += __shfl_xor(ssum, o);
    sv[r] = e / ssum;
  }

  // ---- expert loop: E1 (1-term) -> ehT dbuf (stride 68) -> E2 -> online accum ----
  f32x4 out_acc = (f32x4){0.f,0.f,0.f,0.f};
  const char* webase = ws + OFF_WE;
  #pragma unroll 1
  for (int ke = 0; ke < 10; ++ke){
    const char* wb = webase + ke*WE_STRIDE;
    f32x4 acce[4];
    #pragma unroll
    for (int mt = 0; mt < 4; ++mt) acce[mt] = (f32x4){0.f,0.f,0.f,0.f};
    #pragma unroll
    for (int kc = 0; kc < 4; ++kc){
      bf16x8 bh = gfrag(wb + kc*4096 + w*1024 + l*16);
      #pragma unroll
      for (int mt = 0; mt < 4; ++mt) acce[mt] = MFMA(efh[mt][kc], bh, acce[mt]);
    }
    short* eb = X + (ke & 1)*4352;           // [64][68] shorts (136B rows, conflict-free)
    float bev = be1[ke*64 + w*16 + lr];
    #pragma unroll
    for (int mt = 0; mt < 4; ++mt)
      #pragma unroll
      for (int r = 0; r < 4; ++r){
        int row = mt*16 + lq*4 + r;
        float v = fmaxf(acce[mt][r] + bev, 0.f);
        eb[row*68 + w*16 + lr] = (short)bf16rne(v);
      }
    __syncthreads();
    f32x4 habk = (f32x4){0.f,0.f,0.f,0.f};
    #pragma unroll
    for (int kc2 = 0; kc2 < 2; ++kc2){
      FragU f;
      int rb = (w*16 + lr)*68 + kc2*32 + lq*4;
      f.h[0] = *(const short4*)(eb + rb);
      f.h[1] = *(const short4*)(eb + rb + 16);
      bf16x8 bf2 = gfrag(wb + 32768 + kc2*1024 + l*16);
      habk = MFMA(f.b, bf2, habk);
    }
    float be2v = (lr < 10) ? be2[ke*10 + lr] : 0.f;
    #pragma unroll
    for (int r = 0; r < 4; ++r){
      float sk = __shfl(sv[r], (l & 48) | ke);
      out_acc[r] += (habk[r] + be2v) * sk;
    }
  }

  // ---- coalesced nt output via LDS ----
  float* ob = (float*)(U + 8192);            // 640 f32 (dead region)
  #pragma unroll
  for (int r = 0; r < 4; ++r)
    if (lr < 10) ob[(w*16 + lq*4 + r)*10 + lr] = out_acc[r];
  __syncthreads();
  if (tid < 160) ntstore4(out + (size_t)row0*10 + tid*4, *(const f32x4*)(ob + tid*4));
}

extern "C" void kernel_launch(void* const* d_in, const int* in_sizes, int n_in,
                              void* d_out, int out_size, void* d_ws, size_t ws_size,
                              hipStream_t stream){
  const float* state = (const float*)d_in[0];
  const float* W1    = (const float*)d_in[1];
  const float* b1    = (const float*)d_in[2];
  const float* gamma = (const float*)d_in[3];
  const float* beta  = (const float*)d_in[4];
  const float* W2    = (const float*)d_in[5];
  const float* b2    = (const float*)d_in[6];
  const float* We1   = (const float*)d_in[7];
  const float* be1   = (const float*)d_in[8];
  const float* We2   = (const float*)d_in[9];
  const float* be2   = (const float*)d_in[10];
  const float* attr  = (const float*)d_in[11];
  char* ws  = (char*)d_ws;
  float* out = (float*)d_out;

  k_prep<<<496, 256, 0, stream>>>(W1, We1, We2, attr, ws);
  k_stats<<<1024, 256, 0, stream>>>(state, b1, ws);
  k_finalize<<<1, 256, 0, stream>>>(gamma, beta, ws);
  k_prep2<<<129, 256, 0, stream>>>(W2, b2, ws);
  k_fused<<<4096, 256, 0, stream>>>(state, b1, be1, be2, ws, out);
}